// Round 7
// baseline (250.372 us; speedup 1.0000x reference)
//
#include <hip/hip_runtime.h>
#include <hip/hip_bf16.h>
#include <stdint.h>

#define S_LEN 2688
#define DIM   1536
#define NH    12
#define HD    128
#define QKV_N 4608   // 3*DIM

typedef __attribute__((ext_vector_type(8)))  short bf16x8;
typedef __attribute__((ext_vector_type(4)))  float f32x4;
typedef __attribute__((ext_vector_type(16))) float f32x16;

__device__ inline ushort f2bf(float f) {
    uint32_t u = __float_as_uint(f);
    uint32_t r = (u + 0x7fffu + ((u >> 16) & 1u)) >> 16;
    return (ushort)r;
}

#define GLOAD16(gp, lp) __builtin_amdgcn_global_load_lds( \
    (__attribute__((address_space(1))) const void*)(gp),  \
    (__attribute__((address_space(3))) void*)(lp), 16, 0, 0)

// ---------------------------------------------------------------------------
// 1) fp32 -> bf16 convert: x and the four weight matrices (fused into wb)
// ---------------------------------------------------------------------------
__global__ __launch_bounds__(256) void convert_all(
    const float* __restrict__ x,
    const float* __restrict__ wq, const float* __restrict__ wk,
    const float* __restrict__ wv, const float* __restrict__ wo,
    ushort* __restrict__ xb, ushort* __restrict__ wb)
{
    const size_t NX4 = (size_t)S_LEN * DIM / 4;   // 1,032,192
    const size_t NW4 = (size_t)DIM * DIM / 4;     //   589,824
    size_t i = (size_t)blockIdx.x * 256 + threadIdx.x;
    const float* src; ushort* dst;
    if (i < NX4)            { src = x;  dst = xb; }
    else if (i < NX4+1*NW4) { src = wq; dst = wb;                        i -= NX4; }
    else if (i < NX4+2*NW4) { src = wk; dst = wb + 1*(size_t)DIM*DIM;    i -= NX4+1*NW4; }
    else if (i < NX4+3*NW4) { src = wv; dst = wb + 2*(size_t)DIM*DIM;    i -= NX4+2*NW4; }
    else if (i < NX4+4*NW4) { src = wo; dst = wb + 3*(size_t)DIM*DIM;    i -= NX4+3*NW4; }
    else return;
    float4 v = reinterpret_cast<const float4*>(src)[i];
    ushort4 o = { f2bf(v.x), f2bf(v.y), f2bf(v.z), f2bf(v.w) };
    reinterpret_cast<ushort4*>(dst)[i] = o;
}

// ---------------------------------------------------------------------------
// 2) bf16 GEMM, B^T layout: C[m][n] = sum_k A[m][k]*B[n][k] + bias[n]
//    128x128 tile, BK=64, 4 waves (2x2), 16x16x32 MFMA, global_load_lds w=16
// ---------------------------------------------------------------------------
__global__ __launch_bounds__(256) void gemm_bt(
    const ushort* __restrict__ A, const ushort* __restrict__ B,
    const float* __restrict__ b0, const float* __restrict__ b1,
    const float* __restrict__ b2,
    float* __restrict__ C, int M, int N, int K)
{
    __shared__ ushort At[128 * 64];
    __shared__ ushort Bt[128 * 64];
    const int tid  = threadIdx.x;
    const int wave = tid >> 6, lane = tid & 63;
    const int m0 = blockIdx.x * 128, n0 = blockIdx.y * 128;
    const int wr = wave >> 1, wc = wave & 1;
    const int r = lane & 15, g = lane >> 4;
    const int srow = wave * 8 + (lane >> 3);   // staging row within 32-row chunk
    const int scol = (lane & 7) * 8;           // staging col (8 bf16 = 16B)

    f32x4 acc[4][4] = {};

    for (int k0 = 0; k0 < K; k0 += 64) {
        const ushort* Ag = A + (size_t)m0 * K + k0;
        const ushort* Bg = B + (size_t)n0 * K + k0;
#pragma unroll
        for (int t = 0; t < 4; ++t) {
            GLOAD16(Ag + (size_t)(t*32 + srow) * K + scol, &At[t*2048 + wave*512]);
            GLOAD16(Bg + (size_t)(t*32 + srow) * K + scol, &Bt[t*2048 + wave*512]);
        }
        asm volatile("s_waitcnt vmcnt(0)" ::: "memory");
        __syncthreads();
#pragma unroll
        for (int kk = 0; kk < 2; ++kk) {
            bf16x8 af[4], bfr[4];
#pragma unroll
            for (int i = 0; i < 4; ++i)
                af[i] = *reinterpret_cast<const bf16x8*>(
                    &At[(wr*64 + i*16 + r) * 64 + kk*32 + g*8]);
#pragma unroll
            for (int i = 0; i < 4; ++i)
                bfr[i] = *reinterpret_cast<const bf16x8*>(
                    &Bt[(wc*64 + i*16 + r) * 64 + kk*32 + g*8]);
#pragma unroll
            for (int mi = 0; mi < 4; ++mi)
#pragma unroll
                for (int ni = 0; ni < 4; ++ni)
                    acc[mi][ni] = __builtin_amdgcn_mfma_f32_16x16x32_bf16(
                        af[mi], bfr[ni], acc[mi][ni], 0, 0, 0);
        }
        __syncthreads();
    }

#pragma unroll
    for (int ni = 0; ni < 4; ++ni) {
        int col = n0 + wc*64 + ni*16 + r;
        float bias = (col < DIM) ? b0[col]
                   : (col < 2*DIM) ? b1[col - DIM] : b2[col - 2*DIM];
#pragma unroll
        for (int mi = 0; mi < 4; ++mi) {
            int row = m0 + wr*64 + mi*16 + g*4;
#pragma unroll
            for (int j = 0; j < 4; ++j)
                C[(size_t)(row + j) * N + col] = acc[mi][ni][j] + bias;
        }
    }
}

// ---------------------------------------------------------------------------
// 3) RMS-norm + RoPE for q,k; writes head-major bf16 [n][s][d].
//    1/sqrt(D) attention scale AND log2(e) (for exp2-domain softmax)
//    folded into q.
// ---------------------------------------------------------------------------
__global__ __launch_bounds__(256) void normrope(
    const float* __restrict__ qkv, const int* __restrict__ gsz,
    const float* __restrict__ gq, const float* __restrict__ gk,
    const float* __restrict__ fcos, const float* __restrict__ fsin,
    ushort* __restrict__ q_r, ushort* __restrict__ k_r)
{
    const int s   = blockIdx.x;
    const int tid = threadIdx.x;
    const int wave = tid >> 6, lane = tid & 63;
    const float2* qrow = reinterpret_cast<const float2*>(qkv + (size_t)s * QKV_N);
    const float2* krow = reinterpret_cast<const float2*>(qkv + (size_t)s * QKV_N + DIM);

    float2 qv[3], kv[3];
    float sq = 0.f, sk = 0.f;
#pragma unroll
    for (int i = 0; i < 3; ++i) {
        int p = tid + i*256;
        qv[i] = qrow[p]; kv[i] = krow[p];
        sq += qv[i].x*qv[i].x + qv[i].y*qv[i].y;
        sk += kv[i].x*kv[i].x + kv[i].y*kv[i].y;
    }
#pragma unroll
    for (int off = 1; off < 64; off <<= 1) {
        sq += __shfl_xor(sq, off);
        sk += __shfl_xor(sk, off);
    }
    __shared__ float red[4][2];
    if (lane == 0) { red[wave][0] = sq; red[wave][1] = sk; }
    __syncthreads();
    sq = red[0][0] + red[1][0] + red[2][0] + red[3][0];
    sk = red[0][1] + red[1][1] + red[2][1] + red[3][1];
    const float rmsq = rsqrtf(sq * (1.f/DIM) + 1e-6f);
    const float rmsk = rsqrtf(sk * (1.f/DIM) + 1e-6f);

    const int hh = gsz[1], ww = gsz[2];
    const int fidx = s / (hh*ww), rem = s % (hh*ww);
    const int hidx = rem / ww,  widx = rem % ww;
    // fold 1/sqrt(128) * log2(e): softmax runs in exp2 domain
    const float qscale = rmsq * (0.08838834764831845f * 1.4426950408889634f);

#pragma unroll
    for (int i = 0; i < 3; ++i) {
        int p = tid + i*256;               // pair index 0..767
        int c = p & 63, head = p >> 6;
        int coord = (c < 22) ? fidx : (c < 43) ? hidx : widx;
        float cv = fcos[coord*64 + c], sv = fsin[coord*64 + c];
        float2 gqv = reinterpret_cast<const float2*>(gq)[p];
        float2 gkv = reinterpret_cast<const float2*>(gk)[p];
        float a = qv[i].x * qscale * gqv.x, b = qv[i].y * qscale * gqv.y;
        ushort2 qo = { f2bf(a*cv - b*sv), f2bf(a*sv + b*cv) };
        a = kv[i].x * rmsk * gkv.x; b = kv[i].y * rmsk * gkv.y;
        ushort2 ko = { f2bf(a*cv - b*sv), f2bf(a*sv + b*cv) };
        size_t off = ((size_t)head * S_LEN + s) * HD + 2*c;
        *reinterpret_cast<ushort2*>(q_r + off) = qo;
        *reinterpret_cast<ushort2*>(k_r + off) = ko;
    }
}

// ---------------------------------------------------------------------------
// 4) V: fp32 [s][3*DIM..] slice -> bf16 transposed [n][d][s] via LDS tile
// ---------------------------------------------------------------------------
__global__ __launch_bounds__(256) void vtrans(
    const float* __restrict__ qkv, ushort* __restrict__ v_t)
{
    __shared__ ushort tile[32][33];
    const int s0 = blockIdx.x * 32;
    const int d0 = blockIdx.y * 32;     // within 1536
    const int tid = threadIdx.x;
#pragma unroll
    for (int e = 0; e < 4; ++e) {
        int idx = tid + e*256;
        int sl = idx >> 5, dl = idx & 31;
        tile[dl][sl] = f2bf(qkv[(size_t)(s0+sl) * QKV_N + 2*DIM + d0 + dl]);
    }
    __syncthreads();
#pragma unroll
    for (int e = 0; e < 4; ++e) {
        int idx = tid + e*256;
        int dl = idx >> 5, sl = idx & 31;
        int d = d0 + dl;
        int head = d >> 7, dd = d & 127;
        v_t[((size_t)head * HD + dd) * S_LEN + s0 + sl] = tile[dl][sl];
    }
}

// ---------------------------------------------------------------------------
// 5) Flash attention, 32x32x16 MFMA, swapped operands, in-register P.
//    Wave owns 32 q-rows (q = lane&31, h = lane>>5). Block = 4 waves = 128 q.
//    QK^T: D[key][q] = mfma(K_frag, Q_frag); A row=lane&31, k=(lane>>5)*8+e;
//    C/D: col=lane&31, row=(reg&3)+8*(reg>>2)+4*(lane>>5)  [m74/m101].
//    Softmax in-lane (32 vals) + 1 shfl_xor(32); exp2 domain; defer-max THR=8.
//    P->PV B-frag via 16 v_cvt_pk_bf16_f32 + 8 v_permlane32_swap_b32 (T12):
//    swap(u0,u2),(u1,u3) gives pairs (h*8+0..7) for both halves (i<->i+32
//    preserves q=lane&31). PV: O[d][q] = mfma(V_frag, P_frag).
//    KVBLK=64 dbuf global_load_lds staging, both-sides XOR chunk swizzle
//    (row==lane mod 8 on every read path; 32==0 mod 8).
// ---------------------------------------------------------------------------
__global__ __launch_bounds__(256) void attn_fwd(
    const ushort* __restrict__ q_r, const ushort* __restrict__ k_r,
    const ushort* __restrict__ v_t, const int* __restrict__ seq_lens,
    ushort* __restrict__ attn_out)
{
    __shared__ ushort Kl[2][64 * 128];   // 2 x 16 KB, [key 0..63][chunk swz]
    __shared__ ushort Vl[2][128 * 64];   // 2 x 16 KB, [d 0..127][chunk swz]
    const int tid  = threadIdx.x;
    const int wave = tid >> 6, lane = tid & 63;
    const int n  = blockIdx.y;
    const int seq = seq_lens[0];
    const int ql = lane & 31, h = lane >> 5, sw = lane & 7;
    const int qrow = blockIdx.x * 128 + wave * 32 + ql;
    const ushort* Qh = q_r + (size_t)n * S_LEN * HD;
    const ushort* Kh = k_r + (size_t)n * S_LEN * HD;
    const ushort* Vh = v_t + (size_t)n * HD * S_LEN;

    // staging indices (per thread): chunk j = t*256+tid
    const int kj_row[4] = { (0*256+tid)>>4, (1*256+tid)>>4, (2*256+tid)>>4, (3*256+tid)>>4 };
    const int kj_w  = tid & 15;
    const int vj_d[4]  = { (0*256+tid)>>3, (1*256+tid)>>3, (2*256+tid)>>3, (3*256+tid)>>3 };
    const int vj_w  = tid & 7;

    bf16x8 qf[8];   // Q[qrow][c*16 + h*8 + e]  (B-frag: col=q=ql, k=h*8+e)
#pragma unroll
    for (int c = 0; c < 8; ++c)
        qf[c] = *reinterpret_cast<const bf16x8*>(Qh + (size_t)qrow * HD + c*16 + h*8);

    f32x16 oacc[4] = {};   // oacc[db][j] = O[d = db*32+(j&3)+8*(j>>2)+4h][q=ql]
    float mrun = -1e30f, lrun = 0.f;

    const int nt = (seq + 63) >> 6;

#define STAGE(buf, kbase)                                                     \
    do {                                                                      \
        _Pragma("unroll")                                                     \
        for (int t = 0; t < 4; ++t) {                                         \
            int row = kj_row[t];                                              \
            GLOAD16(Kh + (size_t)((kbase) + row) * HD + ((kj_w ^ (row & 7)) * 8), \
                    &Kl[buf][(t*256 + wave*64) * 8]);                         \
        }                                                                     \
        _Pragma("unroll")                                                     \
        for (int t = 0; t < 4; ++t) {                                         \
            int d = vj_d[t];                                                  \
            GLOAD16(Vh + (size_t)d * S_LEN + (kbase) + ((vj_w ^ (d & 7)) * 8), \
                    &Vl[buf][(t*256 + wave*64) * 8]);                         \
        }                                                                     \
    } while (0)

    STAGE(0, 0);
    asm volatile("s_waitcnt vmcnt(0)" ::: "memory");
    __syncthreads();

    int cur = 0;
    for (int kt = 0; kt < nt; ++kt) {
        const int k0 = kt * 64;
        if (kt + 1 < nt) STAGE(cur ^ 1, k0 + 64);

        // ---- QK^T swapped: sf[kb][j] = S[key = k0+kb*32+(j&3)+8*(j>>2)+4h][q=ql]
        f32x16 sf[2];
#pragma unroll
        for (int kb = 0; kb < 2; ++kb) {
            f32x16 s = {};
            const ushort* kl = &Kl[cur][(kb*32 + ql) * 128];
#pragma unroll
            for (int c = 0; c < 8; ++c)
                s = __builtin_amdgcn_mfma_f32_32x32x16_bf16(
                    *reinterpret_cast<const bf16x8*>(kl + (((2*c + h) ^ sw) * 8)),
                    qf[c], s, 0, 0, 0);
            sf[kb] = s;
        }
        if (k0 + 64 > seq) {   // tail mask (S=2688 divisible by 64; safety only)
#pragma unroll
            for (int kb = 0; kb < 2; ++kb)
#pragma unroll
                for (int j = 0; j < 16; ++j)
                    if (k0 + kb*32 + (j&3) + 8*(j>>2) + 4*h >= seq)
                        sf[kb][j] = -1e30f;
        }
        // ---- in-lane row max (32 vals) + cross-half
        float pm = sf[0][0];
#pragma unroll
        for (int j = 1; j < 16; ++j) pm = fmaxf(pm, sf[0][j]);
#pragma unroll
        for (int j = 0; j < 16; ++j) pm = fmaxf(pm, sf[1][j]);
        pm = fmaxf(pm, __shfl_xor(pm, 32));
        // ---- defer-max (T13): rescale only when max grew past THR (log2 dom.)
        if (!__all(pm - mrun <= 8.f)) {
            float mn = fmaxf(mrun, pm);
            float scl = exp2f(mrun - mn);
            mrun = mn;
            lrun *= scl;
#pragma unroll
            for (int db = 0; db < 4; ++db)
#pragma unroll
                for (int j = 0; j < 16; ++j) oacc[db][j] *= scl;
        }
        // ---- P = exp2(S - mrun), in-lane sum + 1 shfl
        float ps = 0.f;
#pragma unroll
        for (int kb = 0; kb < 2; ++kb)
#pragma unroll
            for (int j = 0; j < 16; ++j) {
                float e = exp2f(sf[kb][j] - mrun);
                sf[kb][j] = e;
                ps += e;
            }
        ps += __shfl_xor(ps, 32);
        lrun += ps;
        // ---- P -> bf16 pairs + permlane32_swap -> PV B-fragments (in-register)
        bf16x8 pfrag[2][2];
#pragma unroll
        for (int kb = 0; kb < 2; ++kb) {
            uint u[8];
#pragma unroll
            for (int i2 = 0; i2 < 8; ++i2)
                asm("v_cvt_pk_bf16_f32 %0, %1, %2"
                    : "=v"(u[i2]) : "v"(sf[kb][2*i2]), "v"(sf[kb][2*i2+1]));
            asm("v_permlane32_swap_b32 %0, %1" : "+v"(u[0]), "+v"(u[2]));
            asm("v_permlane32_swap_b32 %0, %1" : "+v"(u[1]), "+v"(u[3]));
            asm("v_permlane32_swap_b32 %0, %1" : "+v"(u[4]), "+v"(u[6]));
            asm("v_permlane32_swap_b32 %0, %1" : "+v"(u[5]), "+v"(u[7]));
            union { uint uu[4]; bf16x8 v; } a, b;
            a.uu[0] = u[0]; a.uu[1] = u[1]; a.uu[2] = u[2]; a.uu[3] = u[3];
            b.uu[0] = u[4]; b.uu[1] = u[5]; b.uu[2] = u[6]; b.uu[3] = u[7];
            pfrag[kb][0] = a.v;   // keys kb*32 + 0..15
            pfrag[kb][1] = b.v;   // keys kb*32 + 16..31
        }
        // ---- PV swapped: oacc[db] += mfma(V_frag, P_frag) -> O[d][q]
#pragma unroll
        for (int db = 0; db < 4; ++db) {
            const ushort* vl = &Vl[cur][(db*32 + ql) * 64];
#pragma unroll
            for (int kb = 0; kb < 2; ++kb)
#pragma unroll
                for (int kk2 = 0; kk2 < 2; ++kk2)
                    oacc[db] = __builtin_amdgcn_mfma_f32_32x32x16_bf16(
                        *reinterpret_cast<const bf16x8*>(
                            vl + (((4*kb + 2*kk2 + h) ^ sw) * 8)),
                        pfrag[kb][kk2], oacc[db], 0, 0, 0);
        }

        if (kt + 1 < nt) {
            asm volatile("s_waitcnt vmcnt(0)" ::: "memory");
            __syncthreads();
            cur ^= 1;
        }
    }
#undef STAGE

    const float inv = (lrun > 0.f) ? 1.f / lrun : 0.f;
    // lane writes row qrow, d = db*32 + q2*8 + 4h + 0..3 -> 16 b64 stores
#pragma unroll
    for (int db = 0; db < 4; ++db)
#pragma unroll
        for (int q2 = 0; q2 < 4; ++q2) {
            uint2 pkt;
            pkt.x = (uint)f2bf(oacc[db][4*q2+0]*inv) | ((uint)f2bf(oacc[db][4*q2+1]*inv) << 16);
            pkt.y = (uint)f2bf(oacc[db][4*q2+2]*inv) | ((uint)f2bf(oacc[db][4*q2+3]*inv) << 16);
            *reinterpret_cast<uint2*>(
                &attn_out[(size_t)qrow * DIM + n*HD + db*32 + q2*8 + 4*h]) = pkt;
        }
}

// ---------------------------------------------------------------------------
extern "C" void kernel_launch(void* const* d_in, const int* in_sizes, int n_in,
                              void* d_out, int out_size, void* d_ws, size_t ws_size,
                              hipStream_t stream)
{
    const float* x    = (const float*)d_in[0];
    const int*   seqL = (const int*)  d_in[1];
    const int*   gsz  = (const int*)  d_in[2];
    const float* fcos = (const float*)d_in[3];
    const float* fsin = (const float*)d_in[4];
    const float* Wq   = (const float*)d_in[5];
    const float* bq   = (const float*)d_in[6];
    const float* Wk   = (const float*)d_in[7];
    const float* bk   = (const float*)d_in[8];
    const float* Wv   = (const float*)d_in[9];
    const float* bv   = (const float*)d_in[10];
    const float* Wo   = (const float*)d_in[11];
    const float* bo   = (const float*)d_in[12];
    const float* gq   = (const float*)d_in[13];
    const float* gk   = (const float*)d_in[14];
    float* out = (float*)d_out;

    char* ws = (char*)d_ws;
    ushort* xb  = (ushort*)ws;                               // 8,257,536 B
    ushort* wb  = xb + (size_t)S_LEN * DIM;                  // 18,874,368 B
    float*  qkv = (float*)(wb + 4*(size_t)DIM*DIM);          // 49,545,216 B
    ushort* q_r = (ushort*)((char*)qkv + (size_t)S_LEN*QKV_N*4); // 8,257,536 B
    ushort* k_r = q_r + (size_t)S_LEN * DIM;                 // 8,257,536 B
    ushort* v_t = k_r + (size_t)S_LEN * DIM;                 // 8,257,536 B
    ushort* ao  = v_t + (size_t)S_LEN * DIM;                 // 8,257,536 B
    // total ws use: ~109.7 MB

    convert_all<<<13248, 256, 0, stream>>>(x, Wq, Wk, Wv, Wo, xb, wb);
    gemm_bt<<<dim3(21, 36), 256, 0, stream>>>(xb, wb, bq, bk, bv, qkv,
                                              S_LEN, QKV_N, DIM);
    normrope<<<S_LEN, 256, 0, stream>>>(qkv, gsz, gq, gk, fcos, fsin, q_r, k_r);
    vtrans<<<dim3(84, 48), 256, 0, stream>>>(qkv, v_t);
    attn_fwd<<<dim3(21, 12), 256, 0, stream>>>(q_r, k_r, v_t, seqL, ao);
    gemm_bt<<<dim3(21, 12), 256, 0, stream>>>(ao, wb + 3*(size_t)DIM*DIM,
                                              bo, bo, bo, out,
                                              S_LEN, DIM, DIM);
}

// Round 8
// 237.577 us; speedup vs baseline: 1.0539x; 1.0539x over previous
//
#include <hip/hip_runtime.h>
#include <hip/hip_bf16.h>
#include <stdint.h>

#define S_LEN 2688
#define DIM   1536
#define NH    12
#define HD    128
#define QKV_N 4608   // 3*DIM

typedef __attribute__((ext_vector_type(8))) short bf16x8;
typedef __attribute__((ext_vector_type(4))) float f32x4;

__device__ inline ushort f2bf(float f) {
    uint32_t u = __float_as_uint(f);
    uint32_t r = (u + 0x7fffu + ((u >> 16) & 1u)) >> 16;
    return (ushort)r;
}

#define GLOAD16(gp, lp) __builtin_amdgcn_global_load_lds( \
    (__attribute__((address_space(1))) const void*)(gp),  \
    (__attribute__((address_space(3))) void*)(lp), 16, 0, 0)

// ---------------------------------------------------------------------------
// 1) fp32 -> bf16 convert: x and the four weight matrices (fused into wb)
// ---------------------------------------------------------------------------
__global__ __launch_bounds__(256) void convert_all(
    const float* __restrict__ x,
    const float* __restrict__ wq, const float* __restrict__ wk,
    const float* __restrict__ wv, const float* __restrict__ wo,
    ushort* __restrict__ xb, ushort* __restrict__ wb)
{
    const size_t NX4 = (size_t)S_LEN * DIM / 4;   // 1,032,192
    const size_t NW4 = (size_t)DIM * DIM / 4;     //   589,824
    size_t i = (size_t)blockIdx.x * 256 + threadIdx.x;
    const float* src; ushort* dst;
    if (i < NX4)            { src = x;  dst = xb; }
    else if (i < NX4+1*NW4) { src = wq; dst = wb;                        i -= NX4; }
    else if (i < NX4+2*NW4) { src = wk; dst = wb + 1*(size_t)DIM*DIM;    i -= NX4+1*NW4; }
    else if (i < NX4+3*NW4) { src = wv; dst = wb + 2*(size_t)DIM*DIM;    i -= NX4+2*NW4; }
    else if (i < NX4+4*NW4) { src = wo; dst = wb + 3*(size_t)DIM*DIM;    i -= NX4+3*NW4; }
    else return;
    float4 v = reinterpret_cast<const float4*>(src)[i];
    ushort4 o = { f2bf(v.x), f2bf(v.y), f2bf(v.z), f2bf(v.w) };
    reinterpret_cast<ushort4*>(dst)[i] = o;
}

// ---------------------------------------------------------------------------
// 2) bf16 GEMM, B^T layout: C[m][n] = sum_k A[m][k]*B[n][k] + bias[n]
//    128x128 tile, BK=64, 4 waves (2x2), 16x16x32 MFMA, global_load_lds w=16
// ---------------------------------------------------------------------------
__global__ __launch_bounds__(256) void gemm_bt(
    const ushort* __restrict__ A, const ushort* __restrict__ B,
    const float* __restrict__ b0, const float* __restrict__ b1,
    const float* __restrict__ b2,
    float* __restrict__ C, int M, int N, int K)
{
    __shared__ ushort At[128 * 64];
    __shared__ ushort Bt[128 * 64];
    const int tid  = threadIdx.x;
    const int wave = tid >> 6, lane = tid & 63;
    const int m0 = blockIdx.x * 128, n0 = blockIdx.y * 128;
    const int wr = wave >> 1, wc = wave & 1;
    const int r = lane & 15, g = lane >> 4;
    const int srow = wave * 8 + (lane >> 3);   // staging row within 32-row chunk
    const int scol = (lane & 7) * 8;           // staging col (8 bf16 = 16B)

    f32x4 acc[4][4] = {};

    for (int k0 = 0; k0 < K; k0 += 64) {
        const ushort* Ag = A + (size_t)m0 * K + k0;
        const ushort* Bg = B + (size_t)n0 * K + k0;
#pragma unroll
        for (int t = 0; t < 4; ++t) {
            GLOAD16(Ag + (size_t)(t*32 + srow) * K + scol, &At[t*2048 + wave*512]);
            GLOAD16(Bg + (size_t)(t*32 + srow) * K + scol, &Bt[t*2048 + wave*512]);
        }
        asm volatile("s_waitcnt vmcnt(0)" ::: "memory");
        __syncthreads();
#pragma unroll
        for (int kk = 0; kk < 2; ++kk) {
            bf16x8 af[4], bfr[4];
#pragma unroll
            for (int i = 0; i < 4; ++i)
                af[i] = *reinterpret_cast<const bf16x8*>(
                    &At[(wr*64 + i*16 + r) * 64 + kk*32 + g*8]);
#pragma unroll
            for (int i = 0; i < 4; ++i)
                bfr[i] = *reinterpret_cast<const bf16x8*>(
                    &Bt[(wc*64 + i*16 + r) * 64 + kk*32 + g*8]);
#pragma unroll
            for (int mi = 0; mi < 4; ++mi)
#pragma unroll
                for (int ni = 0; ni < 4; ++ni)
                    acc[mi][ni] = __builtin_amdgcn_mfma_f32_16x16x32_bf16(
                        af[mi], bfr[ni], acc[mi][ni], 0, 0, 0);
        }
        __syncthreads();
    }

#pragma unroll
    for (int ni = 0; ni < 4; ++ni) {
        int col = n0 + wc*64 + ni*16 + r;
        float bias = (col < DIM) ? b0[col]
                   : (col < 2*DIM) ? b1[col - DIM] : b2[col - 2*DIM];
#pragma unroll
        for (int mi = 0; mi < 4; ++mi) {
            int row = m0 + wr*64 + mi*16 + g*4;
#pragma unroll
            for (int j = 0; j < 4; ++j)
                C[(size_t)(row + j) * N + col] = acc[mi][ni][j] + bias;
        }
    }
}

// ---------------------------------------------------------------------------
// 2b) bf16 GEMM variant for the out-projection: BM=128, BN=64 tiles ->
//     grid (M/128, N/64) = 504 blocks (2 blocks/CU vs 252 at BN=128).
//     4 waves as 2x2: per-wave 64x32 (acc[4][2]). Same staging pattern.
// ---------------------------------------------------------------------------
__global__ __launch_bounds__(256) void gemm_bt2(
    const ushort* __restrict__ A, const ushort* __restrict__ B,
    const float* __restrict__ b0,
    float* __restrict__ C, int M, int N, int K)
{
    __shared__ ushort At[128 * 64];   // 16 KB
    __shared__ ushort Bt[64 * 64];    //  8 KB
    const int tid  = threadIdx.x;
    const int wave = tid >> 6, lane = tid & 63;
    const int m0 = blockIdx.x * 128, n0 = blockIdx.y * 64;
    const int wr = wave >> 1, wc = wave & 1;
    const int r = lane & 15, g = lane >> 4;
    const int srow = wave * 8 + (lane >> 3);   // A staging row within 32-row chunk
    const int scol = (lane & 7) * 8;
    // B staging: chunk j = t*256+tid, row=j>>3, w=j&7 (64 cols = 8 chunks/row)
    const int brow[2] = { (0*256+tid)>>3, (1*256+tid)>>3 };
    const int bcol = (tid & 7) * 8;

    f32x4 acc[4][2] = {};

    for (int k0 = 0; k0 < K; k0 += 64) {
        const ushort* Ag = A + (size_t)m0 * K + k0;
        const ushort* Bg = B + (size_t)n0 * K + k0;
#pragma unroll
        for (int t = 0; t < 4; ++t)
            GLOAD16(Ag + (size_t)(t*32 + srow) * K + scol, &At[t*2048 + wave*512]);
#pragma unroll
        for (int t = 0; t < 2; ++t)
            GLOAD16(Bg + (size_t)brow[t] * K + bcol, &Bt[(t*256 + wave*64) * 8]);
        asm volatile("s_waitcnt vmcnt(0)" ::: "memory");
        __syncthreads();
#pragma unroll
        for (int kk = 0; kk < 2; ++kk) {
            bf16x8 af[4], bfr[2];
#pragma unroll
            for (int i = 0; i < 4; ++i)
                af[i] = *reinterpret_cast<const bf16x8*>(
                    &At[(wr*64 + i*16 + r) * 64 + kk*32 + g*8]);
#pragma unroll
            for (int i = 0; i < 2; ++i)
                bfr[i] = *reinterpret_cast<const bf16x8*>(
                    &Bt[(wc*32 + i*16 + r) * 64 + kk*32 + g*8]);
#pragma unroll
            for (int mi = 0; mi < 4; ++mi)
#pragma unroll
                for (int ni = 0; ni < 2; ++ni)
                    acc[mi][ni] = __builtin_amdgcn_mfma_f32_16x16x32_bf16(
                        af[mi], bfr[ni], acc[mi][ni], 0, 0, 0);
        }
        __syncthreads();
    }

#pragma unroll
    for (int ni = 0; ni < 2; ++ni) {
        int col = n0 + wc*32 + ni*16 + r;
        float bias = b0[col];
#pragma unroll
        for (int mi = 0; mi < 4; ++mi) {
            int row = m0 + wr*64 + mi*16 + g*4;
#pragma unroll
            for (int j = 0; j < 4; ++j)
                C[(size_t)(row + j) * N + col] = acc[mi][ni][j] + bias;
        }
    }
}

// ---------------------------------------------------------------------------
// 3) RMS-norm + RoPE for q,k; writes head-major bf16 [n][s][d].
//    1/sqrt(D) attention scale AND log2(e) (exp2-domain softmax) folded into q.
// ---------------------------------------------------------------------------
__global__ __launch_bounds__(256) void normrope(
    const float* __restrict__ qkv, const int* __restrict__ gsz,
    const float* __restrict__ gq, const float* __restrict__ gk,
    const float* __restrict__ fcos, const float* __restrict__ fsin,
    ushort* __restrict__ q_r, ushort* __restrict__ k_r)
{
    const int s   = blockIdx.x;
    const int tid = threadIdx.x;
    const int wave = tid >> 6, lane = tid & 63;
    const float2* qrow = reinterpret_cast<const float2*>(qkv + (size_t)s * QKV_N);
    const float2* krow = reinterpret_cast<const float2*>(qkv + (size_t)s * QKV_N + DIM);

    float2 qv[3], kv[3];
    float sq = 0.f, sk = 0.f;
#pragma unroll
    for (int i = 0; i < 3; ++i) {
        int p = tid + i*256;
        qv[i] = qrow[p]; kv[i] = krow[p];
        sq += qv[i].x*qv[i].x + qv[i].y*qv[i].y;
        sk += kv[i].x*kv[i].x + kv[i].y*kv[i].y;
    }
#pragma unroll
    for (int off = 1; off < 64; off <<= 1) {
        sq += __shfl_xor(sq, off);
        sk += __shfl_xor(sk, off);
    }
    __shared__ float red[4][2];
    if (lane == 0) { red[wave][0] = sq; red[wave][1] = sk; }
    __syncthreads();
    sq = red[0][0] + red[1][0] + red[2][0] + red[3][0];
    sk = red[0][1] + red[1][1] + red[2][1] + red[3][1];
    const float rmsq = rsqrtf(sq * (1.f/DIM) + 1e-6f);
    const float rmsk = rsqrtf(sk * (1.f/DIM) + 1e-6f);

    const int hh = gsz[1], ww = gsz[2];
    const int fidx = s / (hh*ww), rem = s % (hh*ww);
    const int hidx = rem / ww,  widx = rem % ww;
    // fold 1/sqrt(128) * log2(e): softmax runs in exp2 domain
    const float qscale = rmsq * (0.08838834764831845f * 1.4426950408889634f);

#pragma unroll
    for (int i = 0; i < 3; ++i) {
        int p = tid + i*256;               // pair index 0..767
        int c = p & 63, head = p >> 6;
        int coord = (c < 22) ? fidx : (c < 43) ? hidx : widx;
        float cv = fcos[coord*64 + c], sv = fsin[coord*64 + c];
        float2 gqv = reinterpret_cast<const float2*>(gq)[p];
        float2 gkv = reinterpret_cast<const float2*>(gk)[p];
        float a = qv[i].x * qscale * gqv.x, b = qv[i].y * qscale * gqv.y;
        ushort2 qo = { f2bf(a*cv - b*sv), f2bf(a*sv + b*cv) };
        a = kv[i].x * rmsk * gkv.x; b = kv[i].y * rmsk * gkv.y;
        ushort2 ko = { f2bf(a*cv - b*sv), f2bf(a*sv + b*cv) };
        size_t off = ((size_t)head * S_LEN + s) * HD + 2*c;
        *reinterpret_cast<ushort2*>(q_r + off) = qo;
        *reinterpret_cast<ushort2*>(k_r + off) = ko;
    }
}

// ---------------------------------------------------------------------------
// 4) V: fp32 [s][3*DIM..] slice -> bf16 transposed [n][d][s] via LDS tile
// ---------------------------------------------------------------------------
__global__ __launch_bounds__(256) void vtrans(
    const float* __restrict__ qkv, ushort* __restrict__ v_t)
{
    __shared__ ushort tile[32][33];
    const int s0 = blockIdx.x * 32;
    const int d0 = blockIdx.y * 32;     // within 1536
    const int tid = threadIdx.x;
#pragma unroll
    for (int e = 0; e < 4; ++e) {
        int idx = tid + e*256;
        int sl = idx >> 5, dl = idx & 31;
        tile[dl][sl] = f2bf(qkv[(size_t)(s0+sl) * QKV_N + 2*DIM + d0 + dl]);
    }
    __syncthreads();
#pragma unroll
    for (int e = 0; e < 4; ++e) {
        int idx = tid + e*256;
        int dl = idx >> 5, sl = idx & 31;
        int d = d0 + dl;
        int head = d >> 7, dd = d & 127;
        v_t[((size_t)head * HD + dd) * S_LEN + s0 + sl] = tile[dl][sl];
    }
}

// ---------------------------------------------------------------------------
// 5) Flash attention (R6-proven 16x16 structure, exp2 domain).
//    LDS-staged, 4 waves/block share one head, swapped operands:
//    scores = mfma(K_frag, Q_frag) -> D[key][q]; in-lane softmax
//    (15-op trees + 2 shfl_xor); defer-max THR=8 (log2 domain);
//    PV swapped: mfma(V_frag, P_frag) -> O[d][q].
//    KVBLK=64, dbuf global_load_lds staging, both-sides XOR chunk swizzle.
// ---------------------------------------------------------------------------
__global__ __launch_bounds__(256) void attn_fwd(
    const ushort* __restrict__ q_r, const ushort* __restrict__ k_r,
    const ushort* __restrict__ v_t, const int* __restrict__ seq_lens,
    ushort* __restrict__ attn_out)
{
    __shared__ ushort Kl[2][64 * 128];   // 2 x 16 KB, [key 0..63][chunk swz]
    __shared__ ushort Vl[2][128 * 64];   // 2 x 16 KB, [d 0..127][chunk swz]
    __shared__ ushort Pl[4][16 * 72];    // per-wave P: [q 0..15][key 0..63], stride 72
    const int tid  = threadIdx.x;
    const int wave = tid >> 6, lane = tid & 63;
    const int n  = blockIdx.y;
    const int q0 = blockIdx.x * 64 + wave * 16;
    const int seq = seq_lens[0];
    const int r = lane & 15, g = lane >> 4;
    const int swz = r & 7;
    const ushort* Qh = q_r + (size_t)n * S_LEN * HD;
    const ushort* Kh = k_r + (size_t)n * S_LEN * HD;
    const ushort* Vh = v_t + (size_t)n * HD * S_LEN;

    // staging indices (per thread): chunk j = t*256+tid
    const int kj_row[4] = { (0*256+tid)>>4, (1*256+tid)>>4, (2*256+tid)>>4, (3*256+tid)>>4 };
    const int kj_w  = tid & 15;
    const int vj_d[4]  = { (0*256+tid)>>3, (1*256+tid)>>3, (2*256+tid)>>3, (3*256+tid)>>3 };
    const int vj_w  = tid & 7;

    bf16x8 qf[4];   // Q[q0+r][c*32+g*8 ..], used as B-fragment (col=q=r)
#pragma unroll
    for (int c = 0; c < 4; ++c)
        qf[c] = *reinterpret_cast<const bf16x8*>(Qh + (size_t)(q0 + r) * HD + c*32 + g*8);

    f32x4 oacc[8] = {};          // oacc[db][j] = O[d=db*16+g*4+j][q=r]
    float mrun = -1e30f, lrun = 0.f;

    const int nt = (seq + 63) >> 6;

#define STAGE(buf, kbase)                                                     \
    do {                                                                      \
        _Pragma("unroll")                                                     \
        for (int t = 0; t < 4; ++t) {                                         \
            int row = kj_row[t];                                              \
            GLOAD16(Kh + (size_t)((kbase) + row) * HD + ((kj_w ^ (row & 7)) * 8), \
                    &Kl[buf][(t*256 + wave*64) * 8]);                         \
        }                                                                     \
        _Pragma("unroll")                                                     \
        for (int t = 0; t < 4; ++t) {                                         \
            int d = vj_d[t];                                                  \
            GLOAD16(Vh + (size_t)d * S_LEN + (kbase) + ((vj_w ^ (d & 7)) * 8), \
                    &Vl[buf][(t*256 + wave*64) * 8]);                         \
        }                                                                     \
    } while (0)

    STAGE(0, 0);
    asm volatile("s_waitcnt vmcnt(0)" ::: "memory");
    __syncthreads();

    int cur = 0;
    for (int kt = 0; kt < nt; ++kt) {
        const int k0 = kt * 64;
        if (kt + 1 < nt) STAGE(cur ^ 1, k0 + 64);

        // ---- QK^T swapped: sf[kb][j] = S[key=k0+kb*16+g*4+j][q=r]
        f32x4 sf[4];
#pragma unroll
        for (int kb = 0; kb < 4; ++kb) {
            f32x4 s = {0.f, 0.f, 0.f, 0.f};
            const ushort* kl = &Kl[cur][(kb*16 + r) * 128];
#pragma unroll
            for (int c = 0; c < 4; ++c)
                s = __builtin_amdgcn_mfma_f32_16x16x32_bf16(
                    *reinterpret_cast<const bf16x8*>(kl + ((4*c + g) ^ swz) * 8),
                    qf[c], s, 0, 0, 0);
            sf[kb] = s;
        }
        if (k0 + 64 > seq) {   // tail mask (never triggers at S=2688, kept for safety)
#pragma unroll
            for (int kb = 0; kb < 4; ++kb)
#pragma unroll
                for (int j = 0; j < 4; ++j)
                    if (k0 + kb*16 + g*4 + j >= seq) sf[kb][j] = -1e30f;
        }
        // ---- in-lane row max over this tile's 16 keys, then across g-groups
        float pm = fmaxf(fmaxf(fmaxf(sf[0][0], sf[0][1]), fmaxf(sf[0][2], sf[0][3])),
                         fmaxf(fmaxf(sf[1][0], sf[1][1]), fmaxf(sf[1][2], sf[1][3])));
        pm = fmaxf(pm, fmaxf(fmaxf(fmaxf(sf[2][0], sf[2][1]), fmaxf(sf[2][2], sf[2][3])),
                             fmaxf(fmaxf(sf[3][0], sf[3][1]), fmaxf(sf[3][2], sf[3][3]))));
        pm = fmaxf(pm, __shfl_xor(pm, 16));
        pm = fmaxf(pm, __shfl_xor(pm, 32));
        // ---- defer-max (T13, THR=8 in log2 domain): rescale only on real growth
        if (!__all(pm - mrun <= 8.f)) {
            float mn = fmaxf(mrun, pm);
            float scl = exp2f(mrun - mn);
            mrun = mn;
            lrun *= scl;
#pragma unroll
            for (int f = 0; f < 8; ++f)
#pragma unroll
                for (int j = 0; j < 4; ++j) oacc[f][j] *= scl;
        }
        // ---- P = exp2(S - mrun) (bounded by 2^8), in-lane sum + 2 shfl
        float ps = 0.f;
#pragma unroll
        for (int kb = 0; kb < 4; ++kb) {
            float e0 = exp2f(sf[kb][0] - mrun), e1 = exp2f(sf[kb][1] - mrun);
            float e2 = exp2f(sf[kb][2] - mrun), e3 = exp2f(sf[kb][3] - mrun);
            sf[kb][0] = e0; sf[kb][1] = e1; sf[kb][2] = e2; sf[kb][3] = e3;
            ps += (e0 + e1) + (e2 + e3);
        }
        ps += __shfl_xor(ps, 16);
        ps += __shfl_xor(ps, 32);
        lrun += ps;
        // ---- P -> LDS: pack 4 bf16 per kb, one b64 write each (addr [q][key])
#pragma unroll
        for (int kb = 0; kb < 4; ++kb) {
            uint2 pkt;
            pkt.x = (uint)f2bf(sf[kb][0]) | ((uint)f2bf(sf[kb][1]) << 16);
            pkt.y = (uint)f2bf(sf[kb][2]) | ((uint)f2bf(sf[kb][3]) << 16);
            *reinterpret_cast<uint2*>(&Pl[wave][r*72 + kb*16 + g*4]) = pkt;
        }
        // P as B-fragment: lane(r,g) needs P[q=r][keys g*8..g*8+7]
        bf16x8 pf[2];
        pf[0] = *reinterpret_cast<const bf16x8*>(&Pl[wave][r*72 + g*8]);
        pf[1] = *reinterpret_cast<const bf16x8*>(&Pl[wave][r*72 + 32 + g*8]);
        // ---- PV swapped: oacc[db] += mfma(V^T_frag, P_frag) -> O[d][q]
#pragma unroll
        for (int db = 0; db < 8; ++db) {
            const ushort* vl = &Vl[cur][(db*16 + r) * 64];
#pragma unroll
            for (int kb2 = 0; kb2 < 2; ++kb2)
                oacc[db] = __builtin_amdgcn_mfma_f32_16x16x32_bf16(
                    *reinterpret_cast<const bf16x8*>(vl + ((kb2*4 + g) ^ swz) * 8),
                    pf[kb2], oacc[db], 0, 0, 0);
        }

        if (kt + 1 < nt) {
            asm volatile("s_waitcnt vmcnt(0)" ::: "memory");
            __syncthreads();
            cur ^= 1;
        }
    }
#undef STAGE

    const float inv = (lrun > 0.f) ? 1.f / lrun : 0.f;
    // row q0+r, cols db*16+g*4+j: pack 4 bf16 -> one b64 store per db
#pragma unroll
    for (int db = 0; db < 8; ++db) {
        uint2 pkt;
        pkt.x = (uint)f2bf(oacc[db][0]*inv) | ((uint)f2bf(oacc[db][1]*inv) << 16);
        pkt.y = (uint)f2bf(oacc[db][2]*inv) | ((uint)f2bf(oacc[db][3]*inv) << 16);
        *reinterpret_cast<uint2*>(
            &attn_out[(size_t)(q0 + r) * DIM + n*HD + db*16 + g*4]) = pkt;
    }
}

// ---------------------------------------------------------------------------
extern "C" void kernel_launch(void* const* d_in, const int* in_sizes, int n_in,
                              void* d_out, int out_size, void* d_ws, size_t ws_size,
                              hipStream_t stream)
{
    const float* x    = (const float*)d_in[0];
    const int*   seqL = (const int*)  d_in[1];
    const int*   gsz  = (const int*)  d_in[2];
    const float* fcos = (const float*)d_in[3];
    const float* fsin = (const float*)d_in[4];
    const float* Wq   = (const float*)d_in[5];
    const float* bq   = (const float*)d_in[6];
    const float* Wk   = (const float*)d_in[7];
    const float* bk   = (const float*)d_in[8];
    const float* Wv   = (const float*)d_in[9];
    const float* bv   = (const float*)d_in[10];
    const float* Wo   = (const float*)d_in[11];
    const float* bo   = (const float*)d_in[12];
    const float* gq   = (const float*)d_in[13];
    const float* gk   = (const float*)d_in[14];
    float* out = (float*)d_out;

    char* ws = (char*)d_ws;
    ushort* xb  = (ushort*)ws;                               // 8,257,536 B
    ushort* wb  = xb + (size_t)S_LEN * DIM;                  // 18,874,368 B
    float*  qkv = (float*)(wb + 4*(size_t)DIM*DIM);          // 49,545,216 B
    ushort* q_r = (ushort*)((char*)qkv + (size_t)S_LEN*QKV_N*4); // 8,257,536 B
    ushort* k_r = q_r + (size_t)S_LEN * DIM;                 // 8,257,536 B
    ushort* v_t = k_r + (size_t)S_LEN * DIM;                 // 8,257,536 B
    ushort* ao  = v_t + (size_t)S_LEN * DIM;                 // 8,257,536 B
    // total ws use: ~109.7 MB

    convert_all<<<13248, 256, 0, stream>>>(x, Wq, Wk, Wv, Wo, xb, wb);
    gemm_bt<<<dim3(21, 36), 256, 0, stream>>>(xb, wb, bq, bk, bv, qkv,
                                              S_LEN, QKV_N, DIM);
    normrope<<<S_LEN, 256, 0, stream>>>(qkv, gsz, gq, gk, fcos, fsin, q_r, k_r);
    vtrans<<<dim3(84, 48), 256, 0, stream>>>(qkv, v_t);
    attn_fwd<<<dim3(42, 12), 256, 0, stream>>>(q_r, k_r, v_t, seqL, ao);
    gemm_bt2<<<dim3(21, 24), 256, 0, stream>>>(ao, wb + 3*(size_t)DIM*DIM,
                                               bo, out, S_LEN, DIM, DIM);
}

// Round 9
// 219.018 us; speedup vs baseline: 1.1432x; 1.0847x over previous
//
#include <hip/hip_runtime.h>
#include <hip/hip_bf16.h>
#include <stdint.h>

#define S_LEN 2688
#define DIM   1536
#define NH    12
#define HD    128
#define QKV_N 4608   // 3*DIM

typedef __attribute__((ext_vector_type(8))) short bf16x8;
typedef __attribute__((ext_vector_type(4))) float f32x4;

__device__ inline ushort f2bf(float f) {
    uint32_t u = __float_as_uint(f);
    uint32_t r = (u + 0x7fffu + ((u >> 16) & 1u)) >> 16;
    return (ushort)r;
}
__device__ inline float bf2f(uint u) { return __uint_as_float(u << 16); }
__device__ inline float fexp2(float x) {           // raw v_exp_f32 (2^x); args
    float r;                                       // bounded by defer-max
    asm("v_exp_f32 %0, %1" : "=v"(r) : "v"(x));
    return r;
}
__device__ inline uint cvtpk(float lo, float hi) { // 2xf32 -> packed bf16
    uint r;
    asm("v_cvt_pk_bf16_f32 %0, %1, %2" : "=v"(r) : "v"(lo), "v"(hi));
    return r;
}

#define GLOAD16(gp, lp) __builtin_amdgcn_global_load_lds( \
    (__attribute__((address_space(1))) const void*)(gp),  \
    (__attribute__((address_space(3))) void*)(lp), 16, 0, 0)

// ---------------------------------------------------------------------------
// 1) fp32 -> bf16 convert: x and the four weight matrices (fused into wb)
// ---------------------------------------------------------------------------
__global__ __launch_bounds__(256) void convert_all(
    const float* __restrict__ x,
    const float* __restrict__ wq, const float* __restrict__ wk,
    const float* __restrict__ wv, const float* __restrict__ wo,
    ushort* __restrict__ xb, ushort* __restrict__ wb)
{
    const size_t NX4 = (size_t)S_LEN * DIM / 4;   // 1,032,192
    const size_t NW4 = (size_t)DIM * DIM / 4;     //   589,824
    size_t i = (size_t)blockIdx.x * 256 + threadIdx.x;
    const float* src; ushort* dst;
    if (i < NX4)            { src = x;  dst = xb; }
    else if (i < NX4+1*NW4) { src = wq; dst = wb;                        i -= NX4; }
    else if (i < NX4+2*NW4) { src = wk; dst = wb + 1*(size_t)DIM*DIM;    i -= NX4+1*NW4; }
    else if (i < NX4+3*NW4) { src = wv; dst = wb + 2*(size_t)DIM*DIM;    i -= NX4+2*NW4; }
    else if (i < NX4+4*NW4) { src = wo; dst = wb + 3*(size_t)DIM*DIM;    i -= NX4+3*NW4; }
    else return;
    float4 v = reinterpret_cast<const float4*>(src)[i];
    ushort4 o = { f2bf(v.x), f2bf(v.y), f2bf(v.z), f2bf(v.w) };
    reinterpret_cast<ushort4*>(dst)[i] = o;
}

// ---------------------------------------------------------------------------
// 2) QKV GEMM, bf16 out: C = x @ [Wq;Wk;Wv]^T + bias.
//    q/k cols (n0<3072) -> qkb [S][3072] bf16 (scalar stores);
//    V cols  (n0>=3072) -> v_t [d][S] bf16 TRANSPOSED (8B packed stores)
//    -- replaces the old fp32 qkv buffer AND the vtrans kernel.
//    128x128 tile, BK=64, 4 waves (2x2), 16x16x32 MFMA, global_load_lds w=16.
// ---------------------------------------------------------------------------
__global__ __launch_bounds__(256) void gemm_qkv(
    const ushort* __restrict__ A, const ushort* __restrict__ B,
    const float* __restrict__ bq, const float* __restrict__ bk,
    const float* __restrict__ bv,
    ushort* __restrict__ qkb, ushort* __restrict__ v_t, int K)
{
    __shared__ ushort At[128 * 64];
    __shared__ ushort Bt[128 * 64];
    const int tid  = threadIdx.x;
    const int wave = tid >> 6, lane = tid & 63;
    const int m0 = blockIdx.x * 128, n0 = blockIdx.y * 128;
    const int wr = wave >> 1, wc = wave & 1;
    const int r = lane & 15, g = lane >> 4;
    const int srow = wave * 8 + (lane >> 3);
    const int scol = (lane & 7) * 8;

    f32x4 acc[4][4] = {};

    for (int k0 = 0; k0 < K; k0 += 64) {
        const ushort* Ag = A + (size_t)m0 * K + k0;
        const ushort* Bg = B + (size_t)n0 * K + k0;
#pragma unroll
        for (int t = 0; t < 4; ++t) {
            GLOAD16(Ag + (size_t)(t*32 + srow) * K + scol, &At[t*2048 + wave*512]);
            GLOAD16(Bg + (size_t)(t*32 + srow) * K + scol, &Bt[t*2048 + wave*512]);
        }
        asm volatile("s_waitcnt vmcnt(0)" ::: "memory");
        __syncthreads();
#pragma unroll
        for (int kk = 0; kk < 2; ++kk) {
            bf16x8 af[4], bfr[4];
#pragma unroll
            for (int i = 0; i < 4; ++i)
                af[i] = *reinterpret_cast<const bf16x8*>(
                    &At[(wr*64 + i*16 + r) * 64 + kk*32 + g*8]);
#pragma unroll
            for (int i = 0; i < 4; ++i)
                bfr[i] = *reinterpret_cast<const bf16x8*>(
                    &Bt[(wc*64 + i*16 + r) * 64 + kk*32 + g*8]);
#pragma unroll
            for (int mi = 0; mi < 4; ++mi)
#pragma unroll
                for (int ni = 0; ni < 4; ++ni)
                    acc[mi][ni] = __builtin_amdgcn_mfma_f32_16x16x32_bf16(
                        af[mi], bfr[ni], acc[mi][ni], 0, 0, 0);
        }
        __syncthreads();
    }

    if (n0 < 2*DIM) {       // q/k region (block-uniform branch)
#pragma unroll
        for (int ni = 0; ni < 4; ++ni) {
            int col = n0 + wc*64 + ni*16 + r;
            float bias = (col < DIM) ? bq[col] : bk[col - DIM];
#pragma unroll
            for (int mi = 0; mi < 4; ++mi) {
                int row = m0 + wr*64 + mi*16 + g*4;
#pragma unroll
                for (int j = 0; j < 4; ++j)
                    qkb[(size_t)(row + j) * (2*DIM) + col] =
                        f2bf(acc[mi][ni][j] + bias);
            }
        }
    } else {                // V region: transposed 8B stores into v_t[d][s]
#pragma unroll
        for (int ni = 0; ni < 4; ++ni) {
            int d = n0 - 2*DIM + wc*64 + ni*16 + r;
            float bias = bv[d];
#pragma unroll
            for (int mi = 0; mi < 4; ++mi) {
                int row = m0 + wr*64 + mi*16 + g*4;
                uint2 pkt;
                pkt.x = cvtpk(acc[mi][ni][0] + bias, acc[mi][ni][1] + bias);
                pkt.y = cvtpk(acc[mi][ni][2] + bias, acc[mi][ni][3] + bias);
                *reinterpret_cast<uint2*>(&v_t[(size_t)d * S_LEN + row]) = pkt;
            }
        }
    }
}

// ---------------------------------------------------------------------------
// 2b) bf16 GEMM for the out-projection: BM=128, BN=64 -> 504 blocks (2/CU).
// ---------------------------------------------------------------------------
__global__ __launch_bounds__(256) void gemm_bt2(
    const ushort* __restrict__ A, const ushort* __restrict__ B,
    const float* __restrict__ b0,
    float* __restrict__ C, int M, int N, int K)
{
    __shared__ ushort At[128 * 64];   // 16 KB
    __shared__ ushort Bt[64 * 64];    //  8 KB
    const int tid  = threadIdx.x;
    const int wave = tid >> 6, lane = tid & 63;
    const int m0 = blockIdx.x * 128, n0 = blockIdx.y * 64;
    const int wr = wave >> 1, wc = wave & 1;
    const int r = lane & 15, g = lane >> 4;
    const int srow = wave * 8 + (lane >> 3);
    const int scol = (lane & 7) * 8;
    const int brow[2] = { (0*256+tid)>>3, (1*256+tid)>>3 };
    const int bcol = (tid & 7) * 8;

    f32x4 acc[4][2] = {};

    for (int k0 = 0; k0 < K; k0 += 64) {
        const ushort* Ag = A + (size_t)m0 * K + k0;
        const ushort* Bg = B + (size_t)n0 * K + k0;
#pragma unroll
        for (int t = 0; t < 4; ++t)
            GLOAD16(Ag + (size_t)(t*32 + srow) * K + scol, &At[t*2048 + wave*512]);
#pragma unroll
        for (int t = 0; t < 2; ++t)
            GLOAD16(Bg + (size_t)brow[t] * K + bcol, &Bt[(t*256 + wave*64) * 8]);
        asm volatile("s_waitcnt vmcnt(0)" ::: "memory");
        __syncthreads();
#pragma unroll
        for (int kk = 0; kk < 2; ++kk) {
            bf16x8 af[4], bfr[2];
#pragma unroll
            for (int i = 0; i < 4; ++i)
                af[i] = *reinterpret_cast<const bf16x8*>(
                    &At[(wr*64 + i*16 + r) * 64 + kk*32 + g*8]);
#pragma unroll
            for (int i = 0; i < 2; ++i)
                bfr[i] = *reinterpret_cast<const bf16x8*>(
                    &Bt[(wc*32 + i*16 + r) * 64 + kk*32 + g*8]);
#pragma unroll
            for (int mi = 0; mi < 4; ++mi)
#pragma unroll
                for (int ni = 0; ni < 2; ++ni)
                    acc[mi][ni] = __builtin_amdgcn_mfma_f32_16x16x32_bf16(
                        af[mi], bfr[ni], acc[mi][ni], 0, 0, 0);
        }
        __syncthreads();
    }

#pragma unroll
    for (int ni = 0; ni < 2; ++ni) {
        int col = n0 + wc*32 + ni*16 + r;
        float bias = b0[col];
#pragma unroll
        for (int mi = 0; mi < 4; ++mi) {
            int row = m0 + wr*64 + mi*16 + g*4;
#pragma unroll
            for (int j = 0; j < 4; ++j)
                C[(size_t)(row + j) * N + col] = acc[mi][ni][j] + bias;
        }
    }
}

// ---------------------------------------------------------------------------
// 3) RMS-norm + RoPE for q,k from bf16 qkb; writes head-major bf16 [n][s][d].
//    1/sqrt(D)*log2(e) folded into q (exp2-domain softmax downstream).
// ---------------------------------------------------------------------------
__global__ __launch_bounds__(256) void normrope(
    const ushort* __restrict__ qkb, const int* __restrict__ gsz,
    const float* __restrict__ gq, const float* __restrict__ gk,
    const float* __restrict__ fcos, const float* __restrict__ fsin,
    ushort* __restrict__ q_r, ushort* __restrict__ k_r)
{
    const int s   = blockIdx.x;
    const int tid = threadIdx.x;
    const int wave = tid >> 6, lane = tid & 63;
    const uint* qrow = reinterpret_cast<const uint*>(qkb + (size_t)s * (2*DIM));
    const uint* krow = qrow + DIM/2;   // 768 uints = 1536 bf16

    float2 qv[3], kv[3];
    float sq = 0.f, sk = 0.f;
#pragma unroll
    for (int i = 0; i < 3; ++i) {
        int p = tid + i*256;
        uint uq = qrow[p], uk = krow[p];
        qv[i].x = bf2f(uq & 0xffffu); qv[i].y = bf2f(uq >> 16);
        kv[i].x = bf2f(uk & 0xffffu); kv[i].y = bf2f(uk >> 16);
        sq += qv[i].x*qv[i].x + qv[i].y*qv[i].y;
        sk += kv[i].x*kv[i].x + kv[i].y*kv[i].y;
    }
#pragma unroll
    for (int off = 1; off < 64; off <<= 1) {
        sq += __shfl_xor(sq, off);
        sk += __shfl_xor(sk, off);
    }
    __shared__ float red[4][2];
    if (lane == 0) { red[wave][0] = sq; red[wave][1] = sk; }
    __syncthreads();
    sq = red[0][0] + red[1][0] + red[2][0] + red[3][0];
    sk = red[0][1] + red[1][1] + red[2][1] + red[3][1];
    const float rmsq = rsqrtf(sq * (1.f/DIM) + 1e-6f);
    const float rmsk = rsqrtf(sk * (1.f/DIM) + 1e-6f);

    const int hh = gsz[1], ww = gsz[2];
    const int fidx = s / (hh*ww), rem = s % (hh*ww);
    const int hidx = rem / ww,  widx = rem % ww;
    // fold 1/sqrt(128) * log2(e): softmax runs in exp2 domain
    const float qscale = rmsq * (0.08838834764831845f * 1.4426950408889634f);

#pragma unroll
    for (int i = 0; i < 3; ++i) {
        int p = tid + i*256;               // pair index 0..767
        int c = p & 63, head = p >> 6;
        int coord = (c < 22) ? fidx : (c < 43) ? hidx : widx;
        float cv = fcos[coord*64 + c], sv = fsin[coord*64 + c];
        float2 gqv = reinterpret_cast<const float2*>(gq)[p];
        float2 gkv = reinterpret_cast<const float2*>(gk)[p];
        float a = qv[i].x * qscale * gqv.x, b = qv[i].y * qscale * gqv.y;
        uint qo = cvtpk(a*cv - b*sv, a*sv + b*cv);
        a = kv[i].x * rmsk * gkv.x; b = kv[i].y * rmsk * gkv.y;
        uint ko = cvtpk(a*cv - b*sv, a*sv + b*cv);
        size_t off = (((size_t)head * S_LEN + s) * HD + 2*c) >> 1;  // uint idx
        reinterpret_cast<uint*>(q_r)[off] = qo;
        reinterpret_cast<uint*>(k_r)[off] = ko;
    }
}

// ---------------------------------------------------------------------------
// 5) Flash attention (R6-proven 16x16 structure), exp2 via raw v_exp_f32,
//    P/O packing via v_cvt_pk_bf16_f32. Swapped operands, in-lane softmax,
//    defer-max THR=8 (log2 domain), KVBLK=64 dbuf global_load_lds staging,
//    both-sides XOR chunk swizzle.
// ---------------------------------------------------------------------------
__global__ __launch_bounds__(256) void attn_fwd(
    const ushort* __restrict__ q_r, const ushort* __restrict__ k_r,
    const ushort* __restrict__ v_t, const int* __restrict__ seq_lens,
    ushort* __restrict__ attn_out)
{
    __shared__ ushort Kl[2][64 * 128];   // 2 x 16 KB
    __shared__ ushort Vl[2][128 * 64];   // 2 x 16 KB
    __shared__ ushort Pl[4][16 * 72];    // per-wave P, stride 72
    const int tid  = threadIdx.x;
    const int wave = tid >> 6, lane = tid & 63;
    const int n  = blockIdx.y;
    const int q0 = blockIdx.x * 64 + wave * 16;
    const int seq = seq_lens[0];
    const int r = lane & 15, g = lane >> 4;
    const int swz = r & 7;
    const ushort* Qh = q_r + (size_t)n * S_LEN * HD;
    const ushort* Kh = k_r + (size_t)n * S_LEN * HD;
    const ushort* Vh = v_t + (size_t)n * HD * S_LEN;

    const int kj_row[4] = { (0*256+tid)>>4, (1*256+tid)>>4, (2*256+tid)>>4, (3*256+tid)>>4 };
    const int kj_w  = tid & 15;
    const int vj_d[4]  = { (0*256+tid)>>3, (1*256+tid)>>3, (2*256+tid)>>3, (3*256+tid)>>3 };
    const int vj_w  = tid & 7;

    bf16x8 qf[4];
#pragma unroll
    for (int c = 0; c < 4; ++c)
        qf[c] = *reinterpret_cast<const bf16x8*>(Qh + (size_t)(q0 + r) * HD + c*32 + g*8);

    f32x4 oacc[8] = {};
    float mrun = -1e30f, lrun = 0.f;

    const int nt = (seq + 63) >> 6;

#define STAGE(buf, kbase)                                                     \
    do {                                                                      \
        _Pragma("unroll")                                                     \
        for (int t = 0; t < 4; ++t) {                                         \
            int row = kj_row[t];                                              \
            GLOAD16(Kh + (size_t)((kbase) + row) * HD + ((kj_w ^ (row & 7)) * 8), \
                    &Kl[buf][(t*256 + wave*64) * 8]);                         \
        }                                                                     \
        _Pragma("unroll")                                                     \
        for (int t = 0; t < 4; ++t) {                                         \
            int d = vj_d[t];                                                  \
            GLOAD16(Vh + (size_t)d * S_LEN + (kbase) + ((vj_w ^ (d & 7)) * 8), \
                    &Vl[buf][(t*256 + wave*64) * 8]);                         \
        }                                                                     \
    } while (0)

    STAGE(0, 0);
    asm volatile("s_waitcnt vmcnt(0)" ::: "memory");
    __syncthreads();

    int cur = 0;
    for (int kt = 0; kt < nt; ++kt) {
        const int k0 = kt * 64;
        if (kt + 1 < nt) STAGE(cur ^ 1, k0 + 64);

        // ---- QK^T swapped: sf[kb][j] = S[key=k0+kb*16+g*4+j][q=r]
        f32x4 sf[4];
#pragma unroll
        for (int kb = 0; kb < 4; ++kb) {
            f32x4 s = {0.f, 0.f, 0.f, 0.f};
            const ushort* kl = &Kl[cur][(kb*16 + r) * 128];
#pragma unroll
            for (int c = 0; c < 4; ++c)
                s = __builtin_amdgcn_mfma_f32_16x16x32_bf16(
                    *reinterpret_cast<const bf16x8*>(kl + ((4*c + g) ^ swz) * 8),
                    qf[c], s, 0, 0, 0);
            sf[kb] = s;
        }
        if (k0 + 64 > seq) {   // tail mask (safety; S=2688 is divisible by 64)
#pragma unroll
            for (int kb = 0; kb < 4; ++kb)
#pragma unroll
                for (int j = 0; j < 4; ++j)
                    if (k0 + kb*16 + g*4 + j >= seq) sf[kb][j] = -1e30f;
        }
        // ---- in-lane row max + 2 shfl
        float pm = fmaxf(fmaxf(fmaxf(sf[0][0], sf[0][1]), fmaxf(sf[0][2], sf[0][3])),
                         fmaxf(fmaxf(sf[1][0], sf[1][1]), fmaxf(sf[1][2], sf[1][3])));
        pm = fmaxf(pm, fmaxf(fmaxf(fmaxf(sf[2][0], sf[2][1]), fmaxf(sf[2][2], sf[2][3])),
                             fmaxf(fmaxf(sf[3][0], sf[3][1]), fmaxf(sf[3][2], sf[3][3]))));
        pm = fmaxf(pm, __shfl_xor(pm, 16));
        pm = fmaxf(pm, __shfl_xor(pm, 32));
        // ---- defer-max (THR=8, log2 domain)
        if (!__all(pm - mrun <= 8.f)) {
            float mn = fmaxf(mrun, pm);
            float scl = fexp2(mrun - mn);
            mrun = mn;
            lrun *= scl;
#pragma unroll
            for (int f = 0; f < 8; ++f)
#pragma unroll
                for (int j = 0; j < 4; ++j) oacc[f][j] *= scl;
        }
        // ---- P = exp2(S - mrun), in-lane sum + 2 shfl
        float ps = 0.f;
#pragma unroll
        for (int kb = 0; kb < 4; ++kb) {
            float e0 = fexp2(sf[kb][0] - mrun), e1 = fexp2(sf[kb][1] - mrun);
            float e2 = fexp2(sf[kb][2] - mrun), e3 = fexp2(sf[kb][3] - mrun);
            sf[kb][0] = e0; sf[kb][1] = e1; sf[kb][2] = e2; sf[kb][3] = e3;
            ps += (e0 + e1) + (e2 + e3);
        }
        ps += __shfl_xor(ps, 16);
        ps += __shfl_xor(ps, 32);
        lrun += ps;
        // ---- P -> LDS via cvt_pk (one b64 write per kb)
#pragma unroll
        for (int kb = 0; kb < 4; ++kb) {
            uint2 pkt;
            pkt.x = cvtpk(sf[kb][0], sf[kb][1]);
            pkt.y = cvtpk(sf[kb][2], sf[kb][3]);
            *reinterpret_cast<uint2*>(&Pl[wave][r*72 + kb*16 + g*4]) = pkt;
        }
        bf16x8 pf[2];
        pf[0] = *reinterpret_cast<const bf16x8*>(&Pl[wave][r*72 + g*8]);
        pf[1] = *reinterpret_cast<const bf16x8*>(&Pl[wave][r*72 + 32 + g*8]);
        // ---- PV swapped: oacc[db] += mfma(V_frag, P_frag) -> O[d][q]
#pragma unroll
        for (int db = 0; db < 8; ++db) {
            const ushort* vl = &Vl[cur][(db*16 + r) * 64];
#pragma unroll
            for (int kb2 = 0; kb2 < 2; ++kb2)
                oacc[db] = __builtin_amdgcn_mfma_f32_16x16x32_bf16(
                    *reinterpret_cast<const bf16x8*>(vl + ((kb2*4 + g) ^ swz) * 8),
                    pf[kb2], oacc[db], 0, 0, 0);
        }

        if (kt + 1 < nt) {
            asm volatile("s_waitcnt vmcnt(0)" ::: "memory");
            __syncthreads();
            cur ^= 1;
        }
    }
#undef STAGE

    const float inv = (lrun > 0.f) ? 1.f / lrun : 0.f;
#pragma unroll
    for (int db = 0; db < 8; ++db) {
        uint2 pkt;
        pkt.x = cvtpk(oacc[db][0]*inv, oacc[db][1]*inv);
        pkt.y = cvtpk(oacc[db][2]*inv, oacc[db][3]*inv);
        *reinterpret_cast<uint2*>(
            &attn_out[(size_t)(q0 + r) * DIM + n*HD + db*16 + g*4]) = pkt;
    }
}

// ---------------------------------------------------------------------------
extern "C" void kernel_launch(void* const* d_in, const int* in_sizes, int n_in,
                              void* d_out, int out_size, void* d_ws, size_t ws_size,
                              hipStream_t stream)
{
    const float* x    = (const float*)d_in[0];
    const int*   seqL = (const int*)  d_in[1];
    const int*   gsz  = (const int*)  d_in[2];
    const float* fcos = (const float*)d_in[3];
    const float* fsin = (const float*)d_in[4];
    const float* Wq   = (const float*)d_in[5];
    const float* bq   = (const float*)d_in[6];
    const float* Wk   = (const float*)d_in[7];
    const float* bk   = (const float*)d_in[8];
    const float* Wv   = (const float*)d_in[9];
    const float* bv   = (const float*)d_in[10];
    const float* Wo   = (const float*)d_in[11];
    const float* bo   = (const float*)d_in[12];
    const float* gq   = (const float*)d_in[13];
    const float* gk   = (const float*)d_in[14];
    float* out = (float*)d_out;

    char* ws = (char*)d_ws;
    ushort* xb  = (ushort*)ws;                     // S*DIM         =  8.26 MB
    ushort* wb  = xb  + (size_t)S_LEN * DIM;       // 4*DIM*DIM     = 18.87 MB
    ushort* qkb = wb  + 4*(size_t)DIM*DIM;         // S*3072        = 16.52 MB
    ushort* v_t = qkb + (size_t)S_LEN * 2*DIM;     // DIM*S         =  8.26 MB
    ushort* q_r = v_t + (size_t)DIM * S_LEN;       // S*DIM         =  8.26 MB
    ushort* k_r = q_r + (size_t)S_LEN * DIM;       // S*DIM         =  8.26 MB
    ushort* ao  = k_r + (size_t)S_LEN * DIM;       // S*DIM         =  8.26 MB
    // total ws use: ~76.7 MB

    convert_all<<<13248, 256, 0, stream>>>(x, Wq, Wk, Wv, Wo, xb, wb);
    gemm_qkv<<<dim3(21, 36), 256, 0, stream>>>(xb, wb, bq, bk, bv,
                                               qkb, v_t, DIM);
    normrope<<<S_LEN, 256, 0, stream>>>(qkb, gsz, gq, gk, fcos, fsin, q_r, k_r);
    attn_fwd<<<dim3(42, 12), 256, 0, stream>>>(q_r, k_r, v_t, seqL, ao);
    gemm_bt2<<<dim3(21, 24), 256, 0, stream>>>(ao, wb + 3*(size_t)DIM*DIM,
                                               bo, out, S_LEN, DIM, DIM);
}